// Round 13
// baseline (1289.956 us; speedup 1.0000x reference)
//
#include <hip/hip_runtime.h>
#include <hip/hip_bf16.h>
#include <math.h>

#define B_    4096
#define V_    9
#define N_    (B_*V_)          // 36864 nodes
#define EK_   (B_*V_*(V_-1))   // 294912 kept edges
#define TPB   1024             // fused-kernel block size (16 waves/CU at 1 block)

typedef unsigned short ushort_t;

__device__ __forceinline__ float b2f(ushort_t u) {
    union { unsigned int i; float f; } x; x.i = ((unsigned int)u) << 16; return x.f;
}
__device__ __forceinline__ ushort_t f2b(float f) {
    union { float f; unsigned int i; } x; x.f = f;
    unsigned int r = x.i + 0x7FFFu + ((x.i >> 16) & 1u);
    return (ushort_t)(r >> 16);
}

// ---------------------------------------------------------------------------
// Batched GEMM for the MLP head: out[M,Nc] = act(A[M,K] @ W[K,Nc] + bias)
// ---------------------------------------------------------------------------
__global__ __launch_bounds__(256) void gemm_act_kernel(
    const float* __restrict__ A, const float* __restrict__ W,
    const float* __restrict__ bias, float* __restrict__ out,
    int K, int Nc, int act)
{
    __shared__ float As[8 * 512];
    const int row0 = blockIdx.x * 8;
    const int tid  = threadIdx.x;

    for (int idx = tid; idx < 8 * K; idx += 256)
        As[idx] = A[row0 * K + idx];
    __syncthreads();

    const int total = 8 * Nc;
    for (int idx = tid; idx < total; idx += 256) {
        int r = idx / Nc;
        int n = idx - r * Nc;
        float acc = bias[n];
        const float* a = &As[r * K];
        for (int k = 0; k < K; ++k)
            acc = fmaf(a[k], W[k * Nc + n], acc);
        if (act == 1) acc = tanhf(acc);
        out[(row0 + r) * Nc + n] = acc;
    }
}

// ---------------------------------------------------------------------------
// One conv layer.  ALL weights read from LDS (bf16) -> inner loops are pure
// LDS traffic, minimal VGPR pressure.  (Global weight loads were the r8/r10/
// r11 spill cause: 14/3.9/0.74 GB scratch per dispatch.)
// ---------------------------------------------------------------------------
template <int XD, int ED2>
__device__ __forceinline__ void conv_layer(
    const float* __restrict__ xs,      // [9][XD] f32 LDS
    const ushort_t* __restrict__ es,   // [81][ED2] bf16 LDS
    const ushort_t* wqL, const ushort_t* wkL,
    const ushort_t* wvL, const ushort_t* weL,
    const float* __restrict__ weo_g,   // [2*XD+ED2][32] f32 global
    ushort_t* weoL,                    // aliases qT (dead after P3)
    ushort_t* qT, ushort_t* kT, ushort_t* vT, ushort_t* eT,
    float* en, float* xn, float* la, int tid)
{
    // P1: q,k,v projections (3*9*128) and e projection (81*128)
    for (int idx = tid; idx < 13824; idx += TPB) {
        if (idx < 3456) {
            int which = idx / 1152, rem = idx - which * 1152;
            int node = rem >> 7, hd = rem & 127;
            int h = hd >> 5, d = hd & 31;
            const ushort_t* w = (which == 0) ? wqL : (which == 1) ? wkL : wvL;
            float acc = 0.f;
            #pragma unroll
            for (int m = 0; m < XD; ++m)
                acc = fmaf(xs[node * XD + m], b2f(w[m * 128 + hd]), acc);
            ushort_t* dst = (which == 0) ? qT : (which == 1) ? kT : vT;
            dst[d * 36 + node * 4 + h] = f2b(acc);
        } else {
            int r = idx - 3456;
            int le = r >> 7, hd = r & 127;
            int h = hd >> 5, d = hd & 31;
            float acc = 0.f;
            #pragma unroll
            for (int m = 0; m < ED2; ++m)
                acc = fmaf(b2f(es[le * ED2 + m]), b2f(weL[m * 128 + hd]), acc);
            eT[d * 324 + le * 4 + h] = f2b(acc);
        }
    }
    __syncthreads();

    // P2a: logits[le,h] = (q[dst=j] . (k[src=i]+e)) / sqrt(32)
    for (int idx = tid; idx < 324; idx += TPB) {
        int le = idx >> 2, h = idx & 3;
        int i = le / 9, j = le - i * 9;
        float acc = 0.f;
        #pragma unroll
        for (int d = 0; d < 32; ++d)
            acc = fmaf(b2f(qT[d * 36 + j * 4 + h]),
                       b2f(kT[d * 36 + i * 4 + h]) + b2f(eT[d * 324 + le * 4 + h]), acc);
        la[idx] = acc * 0.17677669529663687f;
    }
    __syncthreads();

    // P2b: segment softmax over src i, per (dst j, head h), in place
    for (int s = tid; s < 36; s += TPB) {
        int j = s >> 2, h = s & 3;
        float m = -1e30f;
        #pragma unroll
        for (int i = 0; i < 9; ++i) m = fmaxf(m, la[(i * 9 + j) * 4 + h]);
        float ex[9], sum = 0.f;
        #pragma unroll
        for (int i = 0; i < 9; ++i) { ex[i] = __expf(la[(i * 9 + j) * 4 + h] - m); sum += ex[i]; }
        float inv = 1.f / (sum + 1e-16f);
        #pragma unroll
        for (int i = 0; i < 9; ++i) la[(i * 9 + j) * 4 + h] = ex[i] * inv;
    }
    __syncthreads();

    // P3: aggregation -> xn[j,d] = mean_h sum_i alpha * (v[i]+e[le])
    for (int idx = tid; idx < 288; idx += TPB) {
        int j = idx >> 5, d = idx & 31;
        float acc = 0.f;
        #pragma unroll
        for (int h = 0; h < 4; ++h)
            #pragma unroll
            for (int i = 0; i < 9; ++i) {
                int le = i * 9 + j;
                acc = fmaf(la[le * 4 + h],
                           b2f(vT[d * 36 + i * 4 + h]) + b2f(eT[d * 324 + le * 4 + h]), acc);
            }
        xn[idx] = acc * 0.25f;
    }
    __syncthreads();   // qT/kT/vT/eT reads done

    // stage weo (f32 global -> bf16 LDS) into the dead qkv region
    for (int idx = tid; idx < (2 * XD + ED2) * 32; idx += TPB)
        weoL[idx] = f2b(weo_g[idx]);
    __syncthreads();

    // P4: edge out = concat(x[src], x[dst], e) @ weo -> en (aliases eT)
    for (int idx = tid; idx < 2592; idx += TPB) {
        int le = idx >> 5, c = idx & 31;
        int i = le / 9, j = le - i * 9;
        float acc = 0.f;
        #pragma unroll
        for (int m = 0; m < XD;  ++m) acc = fmaf(xs[i * XD + m],        b2f(weoL[m * 32 + c]), acc);
        #pragma unroll
        for (int m = 0; m < XD;  ++m) acc = fmaf(xs[j * XD + m],        b2f(weoL[(XD + m) * 32 + c]), acc);
        #pragma unroll
        for (int m = 0; m < ED2; ++m) acc = fmaf(b2f(es[le * ED2 + m]), b2f(weoL[(2 * XD + m) * 32 + c]), acc);
        en[idx] = acc;
    }
    __syncthreads();   // xs/es reads done before caller overwrites xc/ec
}

// ---------------------------------------------------------------------------
// Fully fused GNN: 3 conv layers + finals.  One block (1024 thr) per graph.
// LDS 70480 B (one allocation/CU); 1024 thr = 16 waves/CU at VGPR<=128
// (r12 measured the code fits 128 VGPR with zero scratch).  r12 at 512 thr
// was 8 waves/CU, VALUBusy 59% -> doubling waves targets the idle 40%.
// ---------------------------------------------------------------------------
__global__ __launch_bounds__(TPB, 4) void fused_gnn_kernel(
    const float* __restrict__ nl,    // [B, 117]
    const float* __restrict__ el,    // [B, 405]
    const float* __restrict__ c0_wq, const float* __restrict__ c0_wk,
    const float* __restrict__ c0_wv, const float* __restrict__ c0_we,
    const float* __restrict__ c0_weo,
    const float* __restrict__ c1_wq, const float* __restrict__ c1_wk,
    const float* __restrict__ c1_wv, const float* __restrict__ c1_we,
    const float* __restrict__ c1_weo,
    const float* __restrict__ ln0_g, const float* __restrict__ ln0_b,
    const float* __restrict__ ln1_g, const float* __restrict__ ln1_b,
    const float* __restrict__ w_feat, const float* __restrict__ w_eout,
    float* __restrict__ out)
{
    __shared__ ushort_t smu[35240];          // 70480 B
    ushort_t* wqL = smu;                     // [<=32][128] bf16
    ushort_t* wkL = smu + 4096;
    ushort_t* wvL = smu + 8192;
    ushort_t* weL = smu + 12288;
    ushort_t* qT  = smu + 16384;             // [32][36]
    ushort_t* kT  = smu + 17536;
    ushort_t* vT  = smu + 18688;
    ushort_t* weoL= smu + 16384;             // alias qkv (3072 <= 3456)
    ushort_t* eT  = smu + 19840;             // [32][324]
    float*    en  = (float*)(smu + 19840);   // 2592 f32, aliases eT
    float*    xc  = (float*)(smu + 30208);   // [9][32] f32
    float*    xn  = (float*)(smu + 30784);   // [9][32] f32
    float*    la  = (float*)(smu + 31360);   // [81][4] f32
    ushort_t* ec  = smu + 32008;             // [81][32] bf16
    float*    x0s = (float*)(smu + 34600);   // [9][13] f32
    ushort_t* e0s = smu + 34834;             // [81][5] bf16

    const int b   = blockIdx.x;
    const int tid = threadIdx.x;

    // stage layer-0 inputs + c0 weights (bf16)
    for (int idx = tid; idx < 117; idx += TPB) x0s[idx] = nl[b * 117 + idx];
    for (int idx = tid; idx < 405; idx += TPB) {
        int le = idx / 5, c = idx - le * 5;
        int i = le / 9, j = le - i * 9;
        e0s[idx] = f2b(0.5f * (el[b * 405 + c * 81 + i * 9 + j] +
                               el[b * 405 + c * 81 + j * 9 + i]));
    }
    for (int idx = tid; idx < 13 * 128; idx += TPB) {
        wqL[idx] = f2b(c0_wq[idx]);
        wkL[idx] = f2b(c0_wk[idx]);
        wvL[idx] = f2b(c0_wv[idx]);
    }
    for (int idx = tid; idx < 5 * 128; idx += TPB) weL[idx] = f2b(c0_we[idx]);
    __syncthreads();

    for (int layer = 0; layer < 3; ++layer) {
        if (layer == 0)
            conv_layer<13, 5>(x0s, e0s, wqL, wkL, wvL, weL, c0_weo, weoL,
                              qT, kT, vT, eT, en, xn, la, tid);
        else
            conv_layer<32, 32>(xc, ec, wqL, wkL, wvL, weL, c1_weo, weoL,
                               qT, kT, vT, eT, en, xn, la, tid);

        // P5 (layers 0,1 only): x = leaky(LN(xn)), e = leaky(en)
        if (layer < 2) {
            const float* g  = (layer == 0) ? ln0_g : ln1_g;
            const float* be = (layer == 0) ? ln0_b : ln1_b;
            for (int idx = tid; idx < 288; idx += TPB) {
                int j = idx >> 5, c = idx & 31;
                float mu = 0.f;
                #pragma unroll
                for (int t = 0; t < 32; ++t) mu += xn[j * 32 + t];
                mu *= (1.f / 32.f);
                float var = 0.f;
                #pragma unroll
                for (int t = 0; t < 32; ++t) { float d = xn[j * 32 + t] - mu; var = fmaf(d, d, var); }
                var *= (1.f / 32.f);
                float val = (xn[idx] - mu) / sqrtf(var + 1e-5f);
                val = val * g[c] + be[c];
                xc[idx] = (val > 0.f) ? val : 0.01f * val;
            }
            for (int idx = tid; idx < 2592; idx += TPB) {
                float v = en[idx];
                ec[idx] = f2b((v > 0.f) ? v : 0.01f * v);
            }
            if (layer == 0) {   // restage weights: c0 -> c1 (layers 1 & 2)
                for (int idx = tid; idx < 32 * 128; idx += TPB) {
                    wqL[idx] = f2b(c1_wq[idx]);
                    wkL[idx] = f2b(c1_wk[idx]);
                    wvL[idx] = f2b(c1_wv[idx]);
                    weL[idx] = f2b(c1_we[idx]);
                }
            }
            __syncthreads();
        }
    }

    // Finals.  After layer 2 (no post): xn [9,32] raw f32, en [81,32] raw f32.
    float* out_x  = out;                       // [36864,10]
    float* out_e  = out + 368640;              // [294912,5]
    float* out_ei = out + 1843200;             // [2,294912]
    float* out_b  = out + 2433024;             // [36864]

    for (int idx = tid; idx < 90; idx += TPB) {         // x @ w_feat
        int j = idx / 10, c = idx - j * 10;
        float acc = 0.f;
        #pragma unroll
        for (int kk = 0; kk < 32; ++kk) acc = fmaf(xn[j * 32 + kk], w_feat[kk * 10 + c], acc);
        out_x[(b * 9 + j) * 10 + c] = acc;
    }
    for (int idx = tid; idx < 360; idx += TPB) {        // masked eattr @ w_eout
        int r = idx / 5, c = idx - r * 5;
        int i = r >> 3, jj = r & 7;
        int j = jj + (jj >= i ? 1 : 0);
        const float* row = &en[(i * 9 + j) * 32];
        float acc = 0.f;
        #pragma unroll
        for (int kk = 0; kk < 32; ++kk) acc = fmaf(row[kk], w_eout[kk * 5 + c], acc);
        out_e[(b * 72 + r) * 5 + c] = acc;
    }
    for (int idx = tid; idx < 72; idx += TPB) {         // edge_index
        int i = idx >> 3, jj = idx & 7;
        int j = jj + (jj >= i ? 1 : 0);
        out_ei[b * 72 + idx]          = (float)(b * 9 + i);
        out_ei[294912 + b * 72 + idx] = (float)(b * 9 + j);
    }
    for (int idx = tid; idx < 9; idx += TPB)            // batch
        out_b[b * 9 + idx] = (float)b;
}

// ---------------------------------------------------------------------------
extern "C" void kernel_launch(void* const* d_in, const int* in_sizes, int n_in,
                              void* d_out, int out_size, void* d_ws, size_t ws_size,
                              hipStream_t stream)
{
    const float* latent  = (const float*)d_in[0];
    const float* w_mlp0  = (const float*)d_in[1];
    const float* b_mlp0  = (const float*)d_in[2];
    const float* w_mlp1  = (const float*)d_in[3];
    const float* b_mlp1  = (const float*)d_in[4];
    const float* w_mlp2  = (const float*)d_in[5];
    const float* b_mlp2  = (const float*)d_in[6];
    const float* w_edges = (const float*)d_in[7];
    const float* b_edges = (const float*)d_in[8];
    const float* w_nodes = (const float*)d_in[9];
    const float* b_nodes = (const float*)d_in[10];
    const float* c0_wq   = (const float*)d_in[11];
    const float* c0_wk   = (const float*)d_in[12];
    const float* c0_wv   = (const float*)d_in[13];
    const float* c0_we   = (const float*)d_in[14];
    const float* c0_weo  = (const float*)d_in[15];
    const float* c1_wq   = (const float*)d_in[16];
    const float* c1_wk   = (const float*)d_in[17];
    const float* c1_wv   = (const float*)d_in[18];
    const float* c1_we   = (const float*)d_in[19];
    const float* c1_weo  = (const float*)d_in[20];
    const float* ln0_g   = (const float*)d_in[21];
    const float* ln0_b   = (const float*)d_in[22];
    const float* ln1_g   = (const float*)d_in[23];
    const float* ln1_b   = (const float*)d_in[24];
    const float* w_feat  = (const float*)d_in[25];
    const float* w_eout  = (const float*)d_in[26];

    // Workspace layout with lifetime overlap (peak 18.3 MB)
    float* ws = (float*)d_ws;
    float* h0 = ws;
    float* el = ws;
    float* h1 = ws + 1658880;
    float* nl = ws + 1658880;
    float* h2 = ws + 2707456;

    float* out = (float*)d_out;

    gemm_act_kernel<<<512, 256, 0, stream>>>(latent, w_mlp0, b_mlp0, h0, 128, 128, 1);
    gemm_act_kernel<<<512, 256, 0, stream>>>(h0, w_mlp1, b_mlp1, h1, 128, 256, 1);
    gemm_act_kernel<<<512, 256, 0, stream>>>(h1, w_mlp2, b_mlp2, h2, 256, 512, 1);
    gemm_act_kernel<<<512, 256, 0, stream>>>(h2, w_edges, b_edges, el, 512, 405, 0);
    gemm_act_kernel<<<512, 256, 0, stream>>>(h2, w_nodes, b_nodes, nl, 512, 117, 0);

    fused_gnn_kernel<<<B_, TPB, 0, stream>>>(nl, el,
        c0_wq, c0_wk, c0_wv, c0_we, c0_weo,
        c1_wq, c1_wk, c1_wv, c1_we, c1_weo,
        ln0_g, ln0_b, ln1_g, ln1_b, w_feat, w_eout, out);
}

// Round 14
// 1287.019 us; speedup vs baseline: 1.0023x; 1.0023x over previous
//
#include <hip/hip_runtime.h>
#include <hip/hip_bf16.h>
#include <math.h>

#define B_    4096
#define V_    9
#define N_    (B_*V_)          // 36864 nodes
#define EK_   (B_*V_*(V_-1))   // 294912 kept edges
#define TPB   1024             // fused-kernel block size (16 waves/CU at 1 block)

typedef unsigned short ushort_t;

__device__ __forceinline__ float b2f(ushort_t u) {
    union { unsigned int i; float f; } x; x.i = ((unsigned int)u) << 16; return x.f;
}
__device__ __forceinline__ ushort_t f2b(float f) {
    union { float f; unsigned int i; } x; x.f = f;
    unsigned int r = x.i + 0x7FFFu + ((x.i >> 16) & 1u);
    return (ushort_t)(r >> 16);
}

// ---------------------------------------------------------------------------
// Batched GEMM for the MLP head: out[M,Nc] = act(A[M,K] @ W[K,Nc] + bias)
// ---------------------------------------------------------------------------
__global__ __launch_bounds__(256) void gemm_act_kernel(
    const float* __restrict__ A, const float* __restrict__ W,
    const float* __restrict__ bias, float* __restrict__ out,
    int K, int Nc, int act)
{
    __shared__ float As[8 * 512];
    const int row0 = blockIdx.x * 8;
    const int tid  = threadIdx.x;

    for (int idx = tid; idx < 8 * K; idx += 256)
        As[idx] = A[row0 * K + idx];
    __syncthreads();

    const int total = 8 * Nc;
    for (int idx = tid; idx < total; idx += 256) {
        int r = idx / Nc;
        int n = idx - r * Nc;
        float acc = bias[n];
        const float* a = &As[r * K];
        for (int k = 0; k < K; ++k)
            acc = fmaf(a[k], W[k * Nc + n], acc);
        if (act == 1) acc = tanhf(acc);
        out[(row0 + r) * Nc + n] = acc;
    }
}

// ---------------------------------------------------------------------------
// One conv layer.  ALL weights read from LDS (bf16) -> inner loops are pure
// LDS traffic, minimal VGPR pressure.  (Global weight loads were the r8/r10/
// r11 spill cause: 14/3.9/0.74 GB scratch per dispatch.)
// ---------------------------------------------------------------------------
template <int XD, int ED2>
__device__ __forceinline__ void conv_layer(
    const float* __restrict__ xs,      // [9][XD] f32 LDS
    const ushort_t* __restrict__ es,   // [81][ED2] bf16 LDS
    const ushort_t* wqL, const ushort_t* wkL,
    const ushort_t* wvL, const ushort_t* weL,
    const float* __restrict__ weo_g,   // [2*XD+ED2][32] f32 global
    ushort_t* weoL,                    // aliases qT (dead after P3)
    ushort_t* qT, ushort_t* kT, ushort_t* vT, ushort_t* eT,
    float* en, float* xn, float* la, int tid)
{
    // P1: q,k,v projections (3*9*128) and e projection (81*128)
    for (int idx = tid; idx < 13824; idx += TPB) {
        if (idx < 3456) {
            int which = idx / 1152, rem = idx - which * 1152;
            int node = rem >> 7, hd = rem & 127;
            int h = hd >> 5, d = hd & 31;
            const ushort_t* w = (which == 0) ? wqL : (which == 1) ? wkL : wvL;
            float acc = 0.f;
            #pragma unroll
            for (int m = 0; m < XD; ++m)
                acc = fmaf(xs[node * XD + m], b2f(w[m * 128 + hd]), acc);
            ushort_t* dst = (which == 0) ? qT : (which == 1) ? kT : vT;
            dst[d * 36 + node * 4 + h] = f2b(acc);
        } else {
            int r = idx - 3456;
            int le = r >> 7, hd = r & 127;
            int h = hd >> 5, d = hd & 31;
            float acc = 0.f;
            #pragma unroll
            for (int m = 0; m < ED2; ++m)
                acc = fmaf(b2f(es[le * ED2 + m]), b2f(weL[m * 128 + hd]), acc);
            eT[d * 324 + le * 4 + h] = f2b(acc);
        }
    }
    __syncthreads();

    // P2a: logits[le,h] = (q[dst=j] . (k[src=i]+e)) / sqrt(32)
    for (int idx = tid; idx < 324; idx += TPB) {
        int le = idx >> 2, h = idx & 3;
        int i = le / 9, j = le - i * 9;
        float acc = 0.f;
        #pragma unroll
        for (int d = 0; d < 32; ++d)
            acc = fmaf(b2f(qT[d * 36 + j * 4 + h]),
                       b2f(kT[d * 36 + i * 4 + h]) + b2f(eT[d * 324 + le * 4 + h]), acc);
        la[idx] = acc * 0.17677669529663687f;
    }
    __syncthreads();

    // P2b: segment softmax over src i, per (dst j, head h), in place
    for (int s = tid; s < 36; s += TPB) {
        int j = s >> 2, h = s & 3;
        float m = -1e30f;
        #pragma unroll
        for (int i = 0; i < 9; ++i) m = fmaxf(m, la[(i * 9 + j) * 4 + h]);
        float ex[9], sum = 0.f;
        #pragma unroll
        for (int i = 0; i < 9; ++i) { ex[i] = __expf(la[(i * 9 + j) * 4 + h] - m); sum += ex[i]; }
        float inv = 1.f / (sum + 1e-16f);
        #pragma unroll
        for (int i = 0; i < 9; ++i) la[(i * 9 + j) * 4 + h] = ex[i] * inv;
    }
    __syncthreads();

    // P3: aggregation -> xn[j,d] = mean_h sum_i alpha * (v[i]+e[le])
    for (int idx = tid; idx < 288; idx += TPB) {
        int j = idx >> 5, d = idx & 31;
        float acc = 0.f;
        #pragma unroll
        for (int h = 0; h < 4; ++h)
            #pragma unroll
            for (int i = 0; i < 9; ++i) {
                int le = i * 9 + j;
                acc = fmaf(la[le * 4 + h],
                           b2f(vT[d * 36 + i * 4 + h]) + b2f(eT[d * 324 + le * 4 + h]), acc);
            }
        xn[idx] = acc * 0.25f;
    }
    __syncthreads();   // qT/kT/vT/eT reads done

    // stage weo (f32 global -> bf16 LDS) into the dead qkv region
    for (int idx = tid; idx < (2 * XD + ED2) * 32; idx += TPB)
        weoL[idx] = f2b(weo_g[idx]);
    __syncthreads();

    // P4: edge out = concat(x[src], x[dst], e) @ weo -> en (aliases eT)
    for (int idx = tid; idx < 2592; idx += TPB) {
        int le = idx >> 5, c = idx & 31;
        int i = le / 9, j = le - i * 9;
        float acc = 0.f;
        #pragma unroll
        for (int m = 0; m < XD;  ++m) acc = fmaf(xs[i * XD + m],        b2f(weoL[m * 32 + c]), acc);
        #pragma unroll
        for (int m = 0; m < XD;  ++m) acc = fmaf(xs[j * XD + m],        b2f(weoL[(XD + m) * 32 + c]), acc);
        #pragma unroll
        for (int m = 0; m < ED2; ++m) acc = fmaf(b2f(es[le * ED2 + m]), b2f(weoL[(2 * XD + m) * 32 + c]), acc);
        en[idx] = acc;
    }
    __syncthreads();   // xs/es reads done before caller overwrites xc/ec
}

// ---------------------------------------------------------------------------
// Fully fused GNN: 3 conv layers + finals.  One block (1024 thr) per graph.
// __launch_bounds__(1024, 2): compiler VGPR cap = 256/arg2 = 128 (formula
// verified across r8/r10/r11/r13: caps 40/64/128/64).  16-wave block at
// VGPR 128 is resident per the m69 ladder (16 waves/CU @ <=128) -> 47%
// occupancy WITHOUT the spills that r13's 64-cap caused (498 MB scratch
// writes -> spill-BW-bound at 945 us).
// ---------------------------------------------------------------------------
__global__ __launch_bounds__(TPB, 2) void fused_gnn_kernel(
    const float* __restrict__ nl,    // [B, 117]
    const float* __restrict__ el,    // [B, 405]
    const float* __restrict__ c0_wq, const float* __restrict__ c0_wk,
    const float* __restrict__ c0_wv, const float* __restrict__ c0_we,
    const float* __restrict__ c0_weo,
    const float* __restrict__ c1_wq, const float* __restrict__ c1_wk,
    const float* __restrict__ c1_wv, const float* __restrict__ c1_we,
    const float* __restrict__ c1_weo,
    const float* __restrict__ ln0_g, const float* __restrict__ ln0_b,
    const float* __restrict__ ln1_g, const float* __restrict__ ln1_b,
    const float* __restrict__ w_feat, const float* __restrict__ w_eout,
    float* __restrict__ out)
{
    __shared__ ushort_t smu[35240];          // 70480 B
    ushort_t* wqL = smu;                     // [<=32][128] bf16
    ushort_t* wkL = smu + 4096;
    ushort_t* wvL = smu + 8192;
    ushort_t* weL = smu + 12288;
    ushort_t* qT  = smu + 16384;             // [32][36]
    ushort_t* kT  = smu + 17536;
    ushort_t* vT  = smu + 18688;
    ushort_t* weoL= smu + 16384;             // alias qkv (3072 <= 3456)
    ushort_t* eT  = smu + 19840;             // [32][324]
    float*    en  = (float*)(smu + 19840);   // 2592 f32, aliases eT
    float*    xc  = (float*)(smu + 30208);   // [9][32] f32
    float*    xn  = (float*)(smu + 30784);   // [9][32] f32
    float*    la  = (float*)(smu + 31360);   // [81][4] f32
    ushort_t* ec  = smu + 32008;             // [81][32] bf16
    float*    x0s = (float*)(smu + 34600);   // [9][13] f32
    ushort_t* e0s = smu + 34834;             // [81][5] bf16

    const int b   = blockIdx.x;
    const int tid = threadIdx.x;

    // stage layer-0 inputs + c0 weights (bf16)
    for (int idx = tid; idx < 117; idx += TPB) x0s[idx] = nl[b * 117 + idx];
    for (int idx = tid; idx < 405; idx += TPB) {
        int le = idx / 5, c = idx - le * 5;
        int i = le / 9, j = le - i * 9;
        e0s[idx] = f2b(0.5f * (el[b * 405 + c * 81 + i * 9 + j] +
                               el[b * 405 + c * 81 + j * 9 + i]));
    }
    for (int idx = tid; idx < 13 * 128; idx += TPB) {
        wqL[idx] = f2b(c0_wq[idx]);
        wkL[idx] = f2b(c0_wk[idx]);
        wvL[idx] = f2b(c0_wv[idx]);
    }
    for (int idx = tid; idx < 5 * 128; idx += TPB) weL[idx] = f2b(c0_we[idx]);
    __syncthreads();

    for (int layer = 0; layer < 3; ++layer) {
        if (layer == 0)
            conv_layer<13, 5>(x0s, e0s, wqL, wkL, wvL, weL, c0_weo, weoL,
                              qT, kT, vT, eT, en, xn, la, tid);
        else
            conv_layer<32, 32>(xc, ec, wqL, wkL, wvL, weL, c1_weo, weoL,
                               qT, kT, vT, eT, en, xn, la, tid);

        // P5 (layers 0,1 only): x = leaky(LN(xn)), e = leaky(en)
        if (layer < 2) {
            const float* g  = (layer == 0) ? ln0_g : ln1_g;
            const float* be = (layer == 0) ? ln0_b : ln1_b;
            for (int idx = tid; idx < 288; idx += TPB) {
                int j = idx >> 5, c = idx & 31;
                float mu = 0.f;
                #pragma unroll
                for (int t = 0; t < 32; ++t) mu += xn[j * 32 + t];
                mu *= (1.f / 32.f);
                float var = 0.f;
                #pragma unroll
                for (int t = 0; t < 32; ++t) { float d = xn[j * 32 + t] - mu; var = fmaf(d, d, var); }
                var *= (1.f / 32.f);
                float val = (xn[idx] - mu) / sqrtf(var + 1e-5f);
                val = val * g[c] + be[c];
                xc[idx] = (val > 0.f) ? val : 0.01f * val;
            }
            for (int idx = tid; idx < 2592; idx += TPB) {
                float v = en[idx];
                ec[idx] = f2b((v > 0.f) ? v : 0.01f * v);
            }
            if (layer == 0) {   // restage weights: c0 -> c1 (layers 1 & 2)
                for (int idx = tid; idx < 32 * 128; idx += TPB) {
                    wqL[idx] = f2b(c1_wq[idx]);
                    wkL[idx] = f2b(c1_wk[idx]);
                    wvL[idx] = f2b(c1_wv[idx]);
                    weL[idx] = f2b(c1_we[idx]);
                }
            }
            __syncthreads();
        }
    }

    // Finals.  After layer 2 (no post): xn [9,32] raw f32, en [81,32] raw f32.
    float* out_x  = out;                       // [36864,10]
    float* out_e  = out + 368640;              // [294912,5]
    float* out_ei = out + 1843200;             // [2,294912]
    float* out_b  = out + 2433024;             // [36864]

    for (int idx = tid; idx < 90; idx += TPB) {         // x @ w_feat
        int j = idx / 10, c = idx - j * 10;
        float acc = 0.f;
        #pragma unroll
        for (int kk = 0; kk < 32; ++kk) acc = fmaf(xn[j * 32 + kk], w_feat[kk * 10 + c], acc);
        out_x[(b * 9 + j) * 10 + c] = acc;
    }
    for (int idx = tid; idx < 360; idx += TPB) {        // masked eattr @ w_eout
        int r = idx / 5, c = idx - r * 5;
        int i = r >> 3, jj = r & 7;
        int j = jj + (jj >= i ? 1 : 0);
        const float* row = &en[(i * 9 + j) * 32];
        float acc = 0.f;
        #pragma unroll
        for (int kk = 0; kk < 32; ++kk) acc = fmaf(row[kk], w_eout[kk * 5 + c], acc);
        out_e[(b * 72 + r) * 5 + c] = acc;
    }
    for (int idx = tid; idx < 72; idx += TPB) {         // edge_index
        int i = idx >> 3, jj = idx & 7;
        int j = jj + (jj >= i ? 1 : 0);
        out_ei[b * 72 + idx]          = (float)(b * 9 + i);
        out_ei[294912 + b * 72 + idx] = (float)(b * 9 + j);
    }
    for (int idx = tid; idx < 9; idx += TPB)            // batch
        out_b[b * 9 + idx] = (float)b;
}

// ---------------------------------------------------------------------------
extern "C" void kernel_launch(void* const* d_in, const int* in_sizes, int n_in,
                              void* d_out, int out_size, void* d_ws, size_t ws_size,
                              hipStream_t stream)
{
    const float* latent  = (const float*)d_in[0];
    const float* w_mlp0  = (const float*)d_in[1];
    const float* b_mlp0  = (const float*)d_in[2];
    const float* w_mlp1  = (const float*)d_in[3];
    const float* b_mlp1  = (const float*)d_in[4];
    const float* w_mlp2  = (const float*)d_in[5];
    const float* b_mlp2  = (const float*)d_in[6];
    const float* w_edges = (const float*)d_in[7];
    const float* b_edges = (const float*)d_in[8];
    const float* w_nodes = (const float*)d_in[9];
    const float* b_nodes = (const float*)d_in[10];
    const float* c0_wq   = (const float*)d_in[11];
    const float* c0_wk   = (const float*)d_in[12];
    const float* c0_wv   = (const float*)d_in[13];
    const float* c0_we   = (const float*)d_in[14];
    const float* c0_weo  = (const float*)d_in[15];
    const float* c1_wq   = (const float*)d_in[16];
    const float* c1_wk   = (const float*)d_in[17];
    const float* c1_wv   = (const float*)d_in[18];
    const float* c1_we   = (const float*)d_in[19];
    const float* c1_weo  = (const float*)d_in[20];
    const float* ln0_g   = (const float*)d_in[21];
    const float* ln0_b   = (const float*)d_in[22];
    const float* ln1_g   = (const float*)d_in[23];
    const float* ln1_b   = (const float*)d_in[24];
    const float* w_feat  = (const float*)d_in[25];
    const float* w_eout  = (const float*)d_in[26];

    // Workspace layout with lifetime overlap (peak 18.3 MB)
    float* ws = (float*)d_ws;
    float* h0 = ws;
    float* el = ws;
    float* h1 = ws + 1658880;
    float* nl = ws + 1658880;
    float* h2 = ws + 2707456;

    float* out = (float*)d_out;

    gemm_act_kernel<<<512, 256, 0, stream>>>(latent, w_mlp0, b_mlp0, h0, 128, 128, 1);
    gemm_act_kernel<<<512, 256, 0, stream>>>(h0, w_mlp1, b_mlp1, h1, 128, 256, 1);
    gemm_act_kernel<<<512, 256, 0, stream>>>(h1, w_mlp2, b_mlp2, h2, 256, 512, 1);
    gemm_act_kernel<<<512, 256, 0, stream>>>(h2, w_edges, b_edges, el, 512, 405, 0);
    gemm_act_kernel<<<512, 256, 0, stream>>>(h2, w_nodes, b_nodes, nl, 512, 117, 0);

    fused_gnn_kernel<<<B_, TPB, 0, stream>>>(nl, el,
        c0_wq, c0_wk, c0_wv, c0_we, c0_weo,
        c1_wq, c1_wk, c1_wv, c1_we, c1_weo,
        ln0_g, ln0_b, ln1_g, ln1_b, w_feat, w_eout, out);
}